// Round 1
// baseline (4558.570 us; speedup 1.0000x reference)
//
#include <hip/hip_runtime.h>
#include <hip/hip_bf16.h>
#include <math.h>

// ---------------------------------------------------------------------------
// VQ-VAE forward on MI355X. Round 0: correctness-first fp32 direct convs.
// Weights read via wave-uniform indices -> scalar loads; inputs coalesced.
// ---------------------------------------------------------------------------

// ---------------- 3x3 conv (stride 1 or 2, pad 1) --------------------------
template<int STRIDE, bool RELU_IN, bool RELU_OUT, int OCB>
__global__ __launch_bounds__(256) void conv3x3_k(
    const float* __restrict__ in, const float* __restrict__ w,
    const float* __restrict__ bias, float* __restrict__ out,
    int Cin, int Hin, int Win, int Cout, int Hout, int wshift)
{
    const int tid = threadIdx.x;
    const int p   = blockIdx.x * 256 + tid;
    const int Wout = 1 << wshift;
    const int oh = p >> wshift, ow = p & (Wout - 1);
    const int b   = blockIdx.z;
    const int oc0 = blockIdx.y * OCB;

    float acc[OCB];
#pragma unroll
    for (int o = 0; o < OCB; ++o) acc[o] = bias ? bias[oc0 + o] : 0.f;

    const int ih0 = oh * STRIDE - 1, iw0 = ow * STRIDE - 1;
    const float* ip = in + (size_t)(b * Cin) * Hin * Win;
    const float* wp = w + (size_t)oc0 * Cin * 9;
    const int wocs = Cin * 9;

    for (int cin = 0; cin < Cin; ++cin) {
        float iv[9];
#pragma unroll
        for (int kh = 0; kh < 3; ++kh) {
#pragma unroll
            for (int kw = 0; kw < 3; ++kw) {
                int ih = ih0 + kh, iw = iw0 + kw;
                bool ok = ((unsigned)ih < (unsigned)Hin) && ((unsigned)iw < (unsigned)Win);
                float v = ok ? ip[ih * Win + iw] : 0.f;
                if (RELU_IN) v = fmaxf(v, 0.f);
                iv[kh * 3 + kw] = v;
            }
        }
        const float* wc = wp + cin * 9;
#pragma unroll
        for (int o = 0; o < OCB; ++o) {
            const float* wo = wc + o * wocs;
#pragma unroll
            for (int k = 0; k < 9; ++k) acc[o] = fmaf(iv[k], wo[k], acc[o]);
        }
        ip += Hin * Win;
    }

    const size_t plane = (size_t)Hout << wshift;
    size_t ob = (size_t)(b * Cout + oc0) * plane + p;
#pragma unroll
    for (int o = 0; o < OCB; ++o) {
        float r = acc[o];
        if (RELU_OUT) r = fmaxf(r, 0.f);
        out[ob + (size_t)o * plane] = r;
    }
}

// ---------------- 1x1 conv (optional residual add, in-place-safe) ----------
template<bool RELU_IN, bool ADD_RES, int OCB>
__global__ __launch_bounds__(256) void conv1x1_k(
    const float* __restrict__ in, const float* __restrict__ w,
    const float* __restrict__ bias, const float* __restrict__ res,
    float* __restrict__ out, int Cin, int HW, int Cout)
{
    const int p   = blockIdx.x * 256 + threadIdx.x;
    const int b   = blockIdx.z;
    const int oc0 = blockIdx.y * OCB;

    float acc[OCB];
#pragma unroll
    for (int o = 0; o < OCB; ++o) acc[o] = bias ? bias[oc0 + o] : 0.f;

    const float* ip = in + (size_t)(b * Cin) * HW + p;
    const float* wp = w + (size_t)oc0 * Cin;
    for (int cin = 0; cin < Cin; ++cin) {
        float v = ip[(size_t)cin * HW];
        if (RELU_IN) v = fmaxf(v, 0.f);
#pragma unroll
        for (int o = 0; o < OCB; ++o) acc[o] = fmaf(v, wp[o * Cin + cin], acc[o]);
    }

#pragma unroll
    for (int o = 0; o < OCB; ++o) {
        size_t idx = (size_t)(b * Cout + oc0 + o) * HW + p;
        float r = acc[o];
        if (ADD_RES) r += res[idx];
        out[idx] = r;
    }
}

// ---------------- ConvTranspose2d k3 s2 p1 outpad1, parity-decomposed ------
template<bool RELU_IN, bool RELU_OUT, int OCB>
__global__ __launch_bounds__(256) void convt_k(
    const float* __restrict__ in, const float* __restrict__ w,
    const float* __restrict__ bias, float* __restrict__ out,
    int Cin, int Hin, int winshift, int Cout, int nyc)
{
    const int Win_ = 1 << winshift;
    const int par   = blockIdx.y / nyc;
    const int ocidx = blockIdx.y % nyc;
    const int po = par >> 1, pw = par & 1;
    const int oc0 = ocidx * OCB;
    const int b = blockIdx.z;

    const int p  = blockIdx.x * 256 + threadIdx.x;
    const int sh = p >> winshift, sw = p & (Win_ - 1);
    const int oh = 2 * sh + po,  ow = 2 * sw + pw;

    // valid taps: oh = 2*ih - 1 + kh  ->  ih = (oh+1-kh)/2 when integral
    int nh, khs[2], ihs[2];
    if (po == 0) { nh = 1; khs[0] = 1; ihs[0] = sh; }
    else         { nh = 2; khs[0] = 0; ihs[0] = sh + 1; khs[1] = 2; ihs[1] = sh; }
    int nw, kws[2], iws[2];
    if (pw == 0) { nw = 1; kws[0] = 1; iws[0] = sw; }
    else         { nw = 2; kws[0] = 0; iws[0] = sw + 1; kws[1] = 2; iws[1] = sw; }

    float acc[OCB];
#pragma unroll
    for (int o = 0; o < OCB; ++o) acc[o] = bias ? bias[oc0 + o] : 0.f;

    const float* ip = in + (size_t)(b * Cin) * Hin * Win_;
    for (int cin = 0; cin < Cin; ++cin) {
#pragma unroll
        for (int a = 0; a < 2; ++a) {
            if (a < nh) {
                bool okh = ihs[a] < Hin;
#pragma unroll
                for (int c = 0; c < 2; ++c) {
                    if (c < nw) {
                        bool ok = okh && (iws[c] < Win_);
                        float v = ok ? ip[ihs[a] * Win_ + iws[c]] : 0.f;
                        if (RELU_IN) v = fmaxf(v, 0.f);
                        const float* wo = w + ((size_t)(cin * Cout + oc0) * 3 + khs[a]) * 3 + kws[c];
#pragma unroll
                        for (int o = 0; o < OCB; ++o)
                            acc[o] = fmaf(v, wo[(size_t)o * 9], acc[o]);
                    }
                }
            }
        }
        ip += Hin * Win_;
    }

    const size_t oplane = (size_t)(4 * Hin) * Win_;  // (2Hin)*(2Win)
    size_t ob = (size_t)(b * Cout + oc0) * oplane + (size_t)oh * (2 * Win_) + ow;
#pragma unroll
    for (int o = 0; o < OCB; ++o) {
        float r = acc[o];
        if (RELU_OUT) r = fmaxf(r, 0.f);
        out[ob + (size_t)o * oplane] = r;
    }
}

// ---------------- codebook squared norms ------------------------------------
__global__ void cnorm_k(const float* __restrict__ cb, float* __restrict__ cnorm)
{
    int k = blockIdx.x * 64 + threadIdx.x;
    float s = 0.f;
#pragma unroll
    for (int d = 0; d < 64; ++d) { float c = cb[k * 64 + d]; s = fmaf(c, c, s); }
    cnorm[k] = s;
}

// ---------------- vector quantization ---------------------------------------
#define VQ_KC 128
__global__ __launch_bounds__(256) void vq_k(
    const float* __restrict__ z, const float* __restrict__ cb,
    const float* __restrict__ cnorm, float* __restrict__ q,
    float* __restrict__ loss_sum, unsigned* __restrict__ hist)
{
    __shared__ float cbs[VQ_KC * 64];
    __shared__ float cns[VQ_KC];
    __shared__ unsigned lh[512];
    __shared__ float werr[4];

    const int tid = threadIdx.x;
    const int g = blockIdx.x * 256 + tid;
    const int b = g >> 10, p = g & 1023;

    for (int i = tid; i < 512; i += 256) lh[i] = 0;

    float zv[64];
    const float* zp = z + (size_t)(b * 64) * 1024 + p;
#pragma unroll
    for (int d = 0; d < 64; ++d) zv[d] = zp[(size_t)d * 1024];

    float best = INFINITY; int bi = 0;
    for (int ch = 0; ch < 512; ch += VQ_KC) {
        __syncthreads();
        const float4* src = (const float4*)(cb + (size_t)ch * 64);
        float4* dst = (float4*)cbs;
        for (int i = tid; i < VQ_KC * 16; i += 256) dst[i] = src[i];
        for (int i = tid; i < VQ_KC; i += 256) cns[i] = cnorm[ch + i];
        __syncthreads();

        for (int k = 0; k < VQ_KC; ++k) {
            const float* cr = cbs + k * 64;
            float dot = 0.f;
#pragma unroll
            for (int d = 0; d < 64; ++d) dot = fmaf(zv[d], cr[d], dot);
            float dist = cns[k] - 2.f * dot;
            if (dist < best) { best = dist; bi = ch + k; }
        }
    }

    // gather winning code, write q, accumulate squared error
    float err = 0.f;
    const float* cr = cb + (size_t)bi * 64;
    float* qp = q + (size_t)(b * 64) * 1024 + p;
#pragma unroll
    for (int d = 0; d < 64; ++d) {
        float c = cr[d];
        float dd = c - zv[d];
        err = fmaf(dd, dd, err);
        qp[(size_t)d * 1024] = c;
    }
    atomicAdd(&lh[bi], 1u);

#pragma unroll
    for (int off = 32; off; off >>= 1) err += __shfl_down(err, off);
    if ((tid & 63) == 0) werr[tid >> 6] = err;
    __syncthreads();
    if (tid == 0) atomicAdd(loss_sum, werr[0] + werr[1] + werr[2] + werr[3]);
    for (int i = tid; i < 512; i += 256) {
        unsigned c = lh[i];
        if (c) atomicAdd(&hist[i], c);
    }
}

// ---------------- finalize loss + perplexity --------------------------------
__global__ void fin_k(const unsigned* __restrict__ hist,
                      const float* __restrict__ loss_sum,
                      float* __restrict__ out, int out_size)
{
    __shared__ float red[512];
    int t = threadIdx.x;
    float pk = (float)hist[t] * (1.f / 32768.f);
    red[t] = pk * logf(pk + 1e-10f);
    __syncthreads();
    for (int s = 256; s; s >>= 1) {
        if (t < s) red[t] += red[t + s];
        __syncthreads();
    }
    if (t == 0) {
        out[0] = 1.25f * loss_sum[0] * (1.f / (32768.f * 64.f));
        out[out_size - 1] = expf(-red[0]);
    }
}

// ---------------------------------------------------------------------------
extern "C" void kernel_launch(void* const* d_in, const int* in_sizes, int n_in,
                              void* d_out, int out_size, void* d_ws, size_t ws_size,
                              hipStream_t stream)
{
    const float* x      = (const float*)d_in[0];
    const float* ec1_w  = (const float*)d_in[1];
    const float* ec1_b  = (const float*)d_in[2];
    const float* ec2_w  = (const float*)d_in[3];
    const float* ec2_b  = (const float*)d_in[4];
    const float* ec3_w  = (const float*)d_in[5];
    const float* ec3_b  = (const float*)d_in[6];
    const float* ec4_w  = (const float*)d_in[7];
    const float* ec4_b  = (const float*)d_in[8];
    const float* er0a_w = (const float*)d_in[9];
    const float* er0b_w = (const float*)d_in[10];
    const float* er1a_w = (const float*)d_in[11];
    const float* er1b_w = (const float*)d_in[12];
    const float* pvq_w  = (const float*)d_in[13];
    const float* pvq_b  = (const float*)d_in[14];
    const float* cbk    = (const float*)d_in[15];
    const float* dc1_w  = (const float*)d_in[16];
    const float* dc1_b  = (const float*)d_in[17];
    const float* dr0a_w = (const float*)d_in[18];
    const float* dr0b_w = (const float*)d_in[19];
    const float* dr1a_w = (const float*)d_in[20];
    const float* dr1b_w = (const float*)d_in[21];
    const float* dt1_w  = (const float*)d_in[22];
    const float* dt1_b  = (const float*)d_in[23];
    const float* dt2_w  = (const float*)d_in[24];
    const float* dt2_b  = (const float*)d_in[25];
    const float* dt3_w  = (const float*)d_in[26];
    const float* dt3_b  = (const float*)d_in[27];

    float* out = (float*)d_out;

    // workspace layout (floats)
    float* bufA = (float*)d_ws;              // 33,554,432  e1 / u2
    float* bufB = bufA + 33554432;           // 16,777,216  e2 / u1
    float* bufC = bufB + 16777216;           //  4,194,304  e3 / d-res chain
    float* bufD = bufC + 4194304;            //  4,194,304  e4/e5/e6 (in-place res)
    float* bufE = bufD + 4194304;            //  1,048,576  res-block hidden t
    float* bufF = bufE + 1048576;            //  2,097,152  z (pre-VQ)
    float* bufG = bufF + 2097152;            //  2,097,152  q (quantized)
    float* cn   = bufG + 2097152;            //  512 codebook norms
    float* lsum = cn + 512;                  //  1 loss accumulator
    unsigned* hist = (unsigned*)(lsum + 1);  //  512 histogram

    hipMemsetAsync(lsum, 0, sizeof(float) * (1 + 512), stream);
    cnorm_k<<<8, 64, 0, stream>>>(cbk, cn);

    // ---- Encoder ----
    conv3x3_k<2, false, true, 4><<<dim3(64, 16, 32), 256, 0, stream>>>(
        x, ec1_w, ec1_b, bufA, 3, 256, 256, 64, 128, 7);
    conv3x3_k<2, false, true, 4><<<dim3(16, 32, 32), 256, 0, stream>>>(
        bufA, ec2_w, ec2_b, bufB, 64, 128, 128, 128, 64, 6);
    conv3x3_k<2, false, true, 4><<<dim3(4, 32, 32), 256, 0, stream>>>(
        bufB, ec3_w, ec3_b, bufC, 128, 64, 64, 128, 32, 5);
    conv3x3_k<1, false, false, 4><<<dim3(4, 32, 32), 256, 0, stream>>>(
        bufC, ec4_w, ec4_b, bufD, 128, 32, 32, 128, 32, 5);
    // residual block 0
    conv3x3_k<1, true, false, 4><<<dim3(4, 8, 32), 256, 0, stream>>>(
        bufD, er0a_w, nullptr, bufE, 128, 32, 32, 32, 32, 5);
    conv1x1_k<true, true, 4><<<dim3(4, 32, 32), 256, 0, stream>>>(
        bufE, er0b_w, nullptr, bufD, bufD, 32, 1024, 128);
    // residual block 1
    conv3x3_k<1, true, false, 4><<<dim3(4, 8, 32), 256, 0, stream>>>(
        bufD, er1a_w, nullptr, bufE, 128, 32, 32, 32, 32, 5);
    conv1x1_k<true, true, 4><<<dim3(4, 32, 32), 256, 0, stream>>>(
        bufE, er1b_w, nullptr, bufD, bufD, 32, 1024, 128);
    // pre-VQ 1x1 (applies final res-stack relu on input)
    conv1x1_k<true, false, 4><<<dim3(4, 16, 32), 256, 0, stream>>>(
        bufD, pvq_w, pvq_b, nullptr, bufF, 128, 1024, 64);

    // ---- VQ ----
    vq_k<<<128, 256, 0, stream>>>(bufF, cbk, cn, bufG, lsum, hist);

    // ---- Decoder ----
    conv3x3_k<1, false, false, 4><<<dim3(4, 32, 32), 256, 0, stream>>>(
        bufG, dc1_w, dc1_b, bufC, 64, 32, 32, 128, 32, 5);
    conv3x3_k<1, true, false, 4><<<dim3(4, 8, 32), 256, 0, stream>>>(
        bufC, dr0a_w, nullptr, bufE, 128, 32, 32, 32, 32, 5);
    conv1x1_k<true, true, 4><<<dim3(4, 32, 32), 256, 0, stream>>>(
        bufE, dr0b_w, nullptr, bufC, bufC, 32, 1024, 128);
    conv3x3_k<1, true, false, 4><<<dim3(4, 8, 32), 256, 0, stream>>>(
        bufC, dr1a_w, nullptr, bufE, 128, 32, 32, 32, 32, 5);
    conv1x1_k<true, true, 4><<<dim3(4, 32, 32), 256, 0, stream>>>(
        bufE, dr1b_w, nullptr, bufC, bufC, 32, 1024, 128);
    // transposed convs (res-stack final relu applied via RELU_IN on dt1)
    convt_k<true, true, 4><<<dim3(4, 64, 32), 256, 0, stream>>>(
        bufC, dt1_w, dt1_b, bufB, 128, 32, 5, 64, 16);
    convt_k<false, true, 4><<<dim3(16, 64, 32), 256, 0, stream>>>(
        bufB, dt2_w, dt2_b, bufA, 64, 64, 6, 64, 16);
    convt_k<false, false, 3><<<dim3(64, 4, 32), 256, 0, stream>>>(
        bufA, dt3_w, dt3_b, out + 1, 64, 128, 7, 3, 1);

    // ---- scalars ----
    fin_k<<<1, 512, 0, stream>>>(hist, lsum, out, out_size);
}

// Round 2
// 983.450 us; speedup vs baseline: 4.6353x; 4.6353x over previous
//
#include <hip/hip_runtime.h>
#include <math.h>

// ---------------------------------------------------------------------------
// VQ-VAE forward, round 1: bf16 MFMA implicit-GEMM convs (NHWC), split-bf16
// (hi+lo) precision for the encoder so VQ argmin matches fp32 reference,
// plain bf16 decoder. ConvT = 4 parity sub-convs via runtime tap tables.
// ---------------------------------------------------------------------------

typedef unsigned short ushort_t;
typedef __bf16 bf8 __attribute__((ext_vector_type(8)));
typedef float f4 __attribute__((ext_vector_type(4)));

struct Taps { int n; int dy[9]; int dx[9]; int wi[9]; };

__device__ __forceinline__ float bf2f(ushort_t u) {
    union { unsigned u; float f; } c; c.u = ((unsigned)u) << 16; return c.f;
}
__device__ __forceinline__ ushort_t f2bf(float f) {
    union { float f; unsigned u; } c; c.f = f; unsigned x = c.u;
    return (ushort_t)((x + 0x7fffu + ((x >> 16) & 1u)) >> 16);
}

// ---------------- weight reorder: fp32 OIHW/IOHW -> bf16 [O][T][I] ----------
__global__ void prep_k(const float* __restrict__ src, ushort_t* __restrict__ dh,
                       ushort_t* __restrict__ dl, int O, int I, int T, int iomode)
{
    int n = O * I * T;
    int id = blockIdx.x * 256 + threadIdx.x;
    if (id >= n) return;
    int i = id % I; int rest = id / I; int t = rest % T; int o = rest / T;
    float v = (iomode == 0) ? src[((size_t)o * I + i) * T + t]
                            : src[((size_t)i * O + o) * T + t];
    ushort_t h = f2bf(v);
    dh[id] = h;
    if (dl) dl[id] = f2bf(v - bf2f(h));
}

// ---------------- MFMA implicit-GEMM conv ----------------------------------
// Tile: M = MW*32 out-channels, N = NW*32 pixels (NW rows x 32 cols of the
// output grid). K-loop over (tap, ci-chunk-of-32). 64*MW*NW = 256 threads.
template<int MW, int NW, int SPLIT, int RELU_IN, int ADD_RES, int OUT_MODE>
__global__ __launch_bounds__(256) void mconv(
    const ushort_t* __restrict__ inH, const ushort_t* __restrict__ inL,
    const ushort_t* __restrict__ wH,  const ushort_t* __restrict__ wL,
    const float* __restrict__ bias,
    const ushort_t* __restrict__ resH, const ushort_t* __restrict__ resL,
    ushort_t* __restrict__ outH, ushort_t* __restrict__ outL,
    float* __restrict__ outF,
    int Cin, int Hin, int Win, int Cout,
    int Hg, int Wg, int S, int wstride,
    int OS, int po, int pw, int Ho, int Wo,
    Taps taps)
{
    constexpr int AR = MW * 32, BR = NW * 32;
    __shared__ ushort_t sAh[AR * 40];
    __shared__ ushort_t sBh[BR * 40];
    __shared__ ushort_t sAl[SPLIT ? AR * 40 : 64];
    __shared__ ushort_t sBl[SPLIT ? BR * 40 : 64];

    const int tid = threadIdx.x;
    const int b   = blockIdx.z;
    const int oc0 = blockIdx.y * (MW * 32);
    const int nTx = Wg >> 5;
    const int ow0 = (blockIdx.x % nTx) * 32;
    const int oh0 = (blockIdx.x / nTx) * NW;

    const int w  = tid >> 6, l = tid & 63;
    const int wm = w % MW, wn = w / MW;
    const int colg = l & 15, kh = l >> 4;

    f4 acc[2][2];
#pragma unroll
    for (int i = 0; i < 2; i++)
#pragma unroll
        for (int j = 0; j < 2; j++) acc[i][j] = (f4)(0.0f);

    const int nch = Cin >> 5;
    for (int t = 0; t < taps.n; ++t) {
        const int dyv = taps.dy[t], dxv = taps.dx[t];
        const size_t wtoff = (size_t)taps.wi[t] * Cin;
        for (int c = 0; c < nch; ++c) {
            __syncthreads();
            // ---- stage A (weights) ----
            {
                const int AU = AR * 4;
                for (int u = tid; u < AU; u += 256) {
                    int oc = u >> 2, sub = u & 3;
                    uint4 vh = {0,0,0,0}, vl = {0,0,0,0};
                    if (oc0 + oc < Cout) {
                        size_t gi = (size_t)(oc0 + oc) * wstride + wtoff + c * 32 + sub * 8;
                        vh = *(const uint4*)(wH + gi);
                        if (SPLIT) vl = *(const uint4*)(wL + gi);
                    }
                    *(uint4*)&sAh[oc * 40 + sub * 8] = vh;
                    if (SPLIT) *(uint4*)&sAl[oc * 40 + sub * 8] = vl;
                }
            }
            // ---- stage B (input pixels) ----
            {
                const int BU = BR * 4;
                for (int u = tid; u < BU; u += 256) {
                    int p = u >> 2, sub = u & 3;
                    int oh = oh0 + (p >> 5), ow = ow0 + (p & 31);
                    int ih = oh * S + dyv, iw = ow * S + dxv;
                    bool ok = ((unsigned)ih < (unsigned)Hin) && ((unsigned)iw < (unsigned)Win);
                    uint4 vh = {0,0,0,0}, vl = {0,0,0,0};
                    if (ok) {
                        size_t gi = (((size_t)(b * Hin) + ih) * Win + iw) * (size_t)Cin + c * 32 + sub * 8;
                        vh = *(const uint4*)(inH + gi);
                        if (SPLIT) vl = *(const uint4*)(inL + gi);
                    }
                    if (RELU_IN) {
                        ushort_t* ph = (ushort_t*)&vh;
                        if (SPLIT) {
                            ushort_t* pl = (ushort_t*)&vl;
#pragma unroll
                            for (int e = 0; e < 8; e++) {
                                float s = bf2f(ph[e]) + bf2f(pl[e]);
                                if (s < 0.f) { ph[e] = 0; pl[e] = 0; }
                            }
                        } else {
#pragma unroll
                            for (int e = 0; e < 8; e++)
                                if (ph[e] & 0x8000u) ph[e] = 0;
                        }
                    }
                    *(uint4*)&sBh[p * 40 + sub * 8] = vh;
                    if (SPLIT) *(uint4*)&sBl[p * 40 + sub * 8] = vl;
                }
            }
            __syncthreads();
            // ---- MFMA ----
            bf8 ah[2], bh[2];
#pragma unroll
            for (int i = 0; i < 2; i++)
                ah[i] = *(const bf8*)&sAh[(wm * 32 + i * 16 + colg) * 40 + kh * 8];
#pragma unroll
            for (int j = 0; j < 2; j++)
                bh[j] = *(const bf8*)&sBh[(wn * 32 + j * 16 + colg) * 40 + kh * 8];
            if (SPLIT) {
                bf8 al[2], bl[2];
#pragma unroll
                for (int i = 0; i < 2; i++)
                    al[i] = *(const bf8*)&sAl[(wm * 32 + i * 16 + colg) * 40 + kh * 8];
#pragma unroll
                for (int j = 0; j < 2; j++)
                    bl[j] = *(const bf8*)&sBl[(wn * 32 + j * 16 + colg) * 40 + kh * 8];
#pragma unroll
                for (int i = 0; i < 2; i++)
#pragma unroll
                    for (int j = 0; j < 2; j++) {
                        acc[i][j] = __builtin_amdgcn_mfma_f32_16x16x32_bf16(ah[i], bh[j], acc[i][j], 0, 0, 0);
                        acc[i][j] = __builtin_amdgcn_mfma_f32_16x16x32_bf16(ah[i], bl[j], acc[i][j], 0, 0, 0);
                        acc[i][j] = __builtin_amdgcn_mfma_f32_16x16x32_bf16(al[i], bh[j], acc[i][j], 0, 0, 0);
                    }
            } else {
#pragma unroll
                for (int i = 0; i < 2; i++)
#pragma unroll
                    for (int j = 0; j < 2; j++)
                        acc[i][j] = __builtin_amdgcn_mfma_f32_16x16x32_bf16(ah[i], bh[j], acc[i][j], 0, 0, 0);
            }
        }
    }

    // ---- store ----
#pragma unroll
    for (int i = 0; i < 2; i++) {
        int ocl = wm * 32 + i * 16 + kh * 4;
        f4 bv = (f4)(0.0f);
        if (OUT_MODE == 0 && bias) bv = *(const f4*)&bias[oc0 + ocl];
#pragma unroll
        for (int j = 0; j < 2; j++) {
            int p  = wn * 32 + j * 16 + colg;
            int oh = oh0 + (p >> 5), ow = ow0 + (p & 31);
            f4 v = acc[i][j];
#pragma unroll
            for (int r = 0; r < 4; r++) v[r] += bv[r];
            if (OUT_MODE == 0) {
                size_t go = (((size_t)(b * Ho) + oh * OS + po) * Wo + (ow * OS + pw)) * (size_t)Cout + oc0 + ocl;
                if (ADD_RES) {
                    uint2 rh = *(const uint2*)&resH[go];
                    v[0] += bf2f((ushort_t)(rh.x & 0xffffu));
                    v[1] += bf2f((ushort_t)(rh.x >> 16));
                    v[2] += bf2f((ushort_t)(rh.y & 0xffffu));
                    v[3] += bf2f((ushort_t)(rh.y >> 16));
                    if (SPLIT) {
                        uint2 rl = *(const uint2*)&resL[go];
                        v[0] += bf2f((ushort_t)(rl.x & 0xffffu));
                        v[1] += bf2f((ushort_t)(rl.x >> 16));
                        v[2] += bf2f((ushort_t)(rl.y & 0xffffu));
                        v[3] += bf2f((ushort_t)(rl.y >> 16));
                    }
                }
                ushort_t h0 = f2bf(v[0]), h1 = f2bf(v[1]), h2 = f2bf(v[2]), h3 = f2bf(v[3]);
                uint2 sh;
                sh.x = (unsigned)h0 | ((unsigned)h1 << 16);
                sh.y = (unsigned)h2 | ((unsigned)h3 << 16);
                *(uint2*)&outH[go] = sh;
                if (SPLIT) {
                    ushort_t l0 = f2bf(v[0] - bf2f(h0)), l1 = f2bf(v[1] - bf2f(h1));
                    ushort_t l2 = f2bf(v[2] - bf2f(h2)), l3 = f2bf(v[3] - bf2f(h3));
                    uint2 sl;
                    sl.x = (unsigned)l0 | ((unsigned)l1 << 16);
                    sl.y = (unsigned)l2 | ((unsigned)l3 << 16);
                    *(uint2*)&outL[go] = sl;
                }
            } else {
#pragma unroll
                for (int r = 0; r < 4; r++) {
                    int oc = ocl + r;
                    if (oc < Cout) {
                        float vb = v[r] + (bias ? bias[oc] : 0.f);
                        outF[(((size_t)(b * Cout) + oc) * Ho + oh * OS + po) * Wo + ow * OS + pw] = vb;
                    }
                }
            }
        }
    }
}

// ---------------- ec1: fp32 NCHW x -> split bf16 NHWC (Cin=3) --------------
__global__ __launch_bounds__(256) void ec1_k(
    const float* __restrict__ x, const float* __restrict__ wt,
    const float* __restrict__ bias, ushort_t* __restrict__ outH, ushort_t* __restrict__ outL)
{
    const int tid = threadIdx.x;
    const int p = blockIdx.x * 256 + tid;       // 16384 px per image
    const int b = blockIdx.z;
    const int oc0 = blockIdx.y * 16;
    const int oh = p >> 7, ow = p & 127;

    float acc[16];
#pragma unroll
    for (int o = 0; o < 16; ++o) acc[o] = bias[oc0 + o];

    const int ih0 = oh * 2 - 1, iw0 = ow * 2 - 1;
    for (int ci = 0; ci < 3; ++ci) {
        float iv[9];
#pragma unroll
        for (int kh = 0; kh < 3; ++kh)
#pragma unroll
            for (int kw = 0; kw < 3; ++kw) {
                int ih = ih0 + kh, iw = iw0 + kw;
                bool ok = ((unsigned)ih < 256u) && ((unsigned)iw < 256u);
                iv[kh * 3 + kw] = ok ? x[(((size_t)(b * 3) + ci) * 256 + ih) * 256 + iw] : 0.f;
            }
#pragma unroll
        for (int o = 0; o < 16; ++o) {
            const float* wp = wt + ((size_t)(oc0 + o) * 3 + ci) * 9;
#pragma unroll
            for (int k = 0; k < 9; ++k) acc[o] = fmaf(iv[k], wp[k], acc[o]);
        }
    }

    size_t go = (((size_t)(b * 128) + oh) * 128 + ow) * 64 + oc0;
    unsigned uh[8], ul[8];
#pragma unroll
    for (int e = 0; e < 8; ++e) {
        ushort_t h0 = f2bf(acc[2 * e]), h1 = f2bf(acc[2 * e + 1]);
        ushort_t g0 = f2bf(acc[2 * e] - bf2f(h0)), g1 = f2bf(acc[2 * e + 1] - bf2f(h1));
        uh[e] = (unsigned)h0 | ((unsigned)h1 << 16);
        ul[e] = (unsigned)g0 | ((unsigned)g1 << 16);
    }
    uint4 s0 = {uh[0], uh[1], uh[2], uh[3]}, s1 = {uh[4], uh[5], uh[6], uh[7]};
    uint4 t0 = {ul[0], ul[1], ul[2], ul[3]}, t1 = {ul[4], ul[5], ul[6], ul[7]};
    *(uint4*)&outH[go] = s0; *(uint4*)&outH[go + 8] = s1;
    *(uint4*)&outL[go] = t0; *(uint4*)&outL[go + 8] = t1;
}

// ---------------- codebook squared norms ------------------------------------
__global__ void cnorm_k(const float* __restrict__ cb, float* __restrict__ cnorm)
{
    int k = blockIdx.x * 64 + threadIdx.x;
    float s = 0.f;
#pragma unroll
    for (int d = 0; d < 64; ++d) { float c = cb[(size_t)k * 64 + d]; s = fmaf(c, c, s); }
    cnorm[k] = s;
}

// ---------------- vector quantization ---------------------------------------
#define VQ_KC 128
__global__ __launch_bounds__(256) void vq_k(
    const ushort_t* __restrict__ zH, const ushort_t* __restrict__ zL,
    const float* __restrict__ cb, const float* __restrict__ cnorm,
    ushort_t* __restrict__ q, float* __restrict__ lsum, unsigned* __restrict__ hist)
{
    __shared__ float cbs[VQ_KC * 64];
    __shared__ float cns[VQ_KC];
    __shared__ unsigned lh[512];
    __shared__ float werr[4];

    const int tid = threadIdx.x;
    const int pix = blockIdx.x * 256 + tid;

    for (int i = tid; i < 512; i += 256) lh[i] = 0;

    float zv[64];
#pragma unroll
    for (int g = 0; g < 8; ++g) {
        uint4 h4 = *(const uint4*)&zH[(size_t)pix * 64 + g * 8];
        uint4 l4 = *(const uint4*)&zL[(size_t)pix * 64 + g * 8];
        const unsigned* hp = (const unsigned*)&h4;
        const unsigned* lp = (const unsigned*)&l4;
#pragma unroll
        for (int e = 0; e < 4; ++e) {
            zv[g * 8 + 2 * e]     = bf2f((ushort_t)(hp[e] & 0xffffu)) + bf2f((ushort_t)(lp[e] & 0xffffu));
            zv[g * 8 + 2 * e + 1] = bf2f((ushort_t)(hp[e] >> 16))     + bf2f((ushort_t)(lp[e] >> 16));
        }
    }

    float best = INFINITY; int bi = 0;
    for (int ch = 0; ch < 512; ch += VQ_KC) {
        __syncthreads();
        const f4* src = (const f4*)(cb + (size_t)ch * 64);
        f4* dst = (f4*)cbs;
        for (int i = tid; i < VQ_KC * 16; i += 256) dst[i] = src[i];
        for (int i = tid; i < VQ_KC; i += 256) cns[i] = cnorm[ch + i];
        __syncthreads();

        for (int k = 0; k < VQ_KC; ++k) {
            const f4* cr = (const f4*)(cbs + k * 64);
            float dot = 0.f;
#pragma unroll
            for (int d = 0; d < 16; ++d) {
                f4 cv = cr[d];
                dot = fmaf(zv[4 * d],     cv[0], dot);
                dot = fmaf(zv[4 * d + 1], cv[1], dot);
                dot = fmaf(zv[4 * d + 2], cv[2], dot);
                dot = fmaf(zv[4 * d + 3], cv[3], dot);
            }
            float dist = cns[k] - 2.f * dot;
            if (dist < best) { best = dist; bi = ch + k; }
        }
    }

    float err = 0.f;
    const float* cr = cb + (size_t)bi * 64;
#pragma unroll
    for (int g = 0; g < 8; ++g) {
        ushort_t hh[8];
#pragma unroll
        for (int e = 0; e < 8; ++e) {
            float c = cr[g * 8 + e];
            float dd = c - zv[g * 8 + e];
            err = fmaf(dd, dd, err);
            hh[e] = f2bf(c);
        }
        uint4 st;
        st.x = (unsigned)hh[0] | ((unsigned)hh[1] << 16);
        st.y = (unsigned)hh[2] | ((unsigned)hh[3] << 16);
        st.z = (unsigned)hh[4] | ((unsigned)hh[5] << 16);
        st.w = (unsigned)hh[6] | ((unsigned)hh[7] << 16);
        *(uint4*)&q[(size_t)pix * 64 + g * 8] = st;
    }
    atomicAdd(&lh[bi], 1u);

#pragma unroll
    for (int off = 32; off; off >>= 1) err += __shfl_down(err, off);
    if ((tid & 63) == 0) werr[tid >> 6] = err;
    __syncthreads();
    if (tid == 0) atomicAdd(lsum, werr[0] + werr[1] + werr[2] + werr[3]);
    for (int i = tid; i < 512; i += 256) {
        unsigned c = lh[i];
        if (c) atomicAdd(&hist[i], c);
    }
}

// ---------------- finalize loss + perplexity --------------------------------
__global__ void fin_k(const unsigned* __restrict__ hist,
                      const float* __restrict__ loss_sum,
                      float* __restrict__ out, int out_size)
{
    __shared__ float red[512];
    int t = threadIdx.x;
    float pk = (float)hist[t] * (1.f / 32768.f);
    red[t] = pk * logf(pk + 1e-10f);
    __syncthreads();
    for (int s = 256; s; s >>= 1) {
        if (t < s) red[t] += red[t + s];
        __syncthreads();
    }
    if (t == 0) {
        out[0] = 1.25f * loss_sum[0] * (1.f / (32768.f * 64.f));
        out[out_size - 1] = expf(-red[0]);
    }
}

// ---------------------------------------------------------------------------
extern "C" void kernel_launch(void* const* d_in, const int* in_sizes, int n_in,
                              void* d_out, int out_size, void* d_ws, size_t ws_size,
                              hipStream_t stream)
{
    const float* x      = (const float*)d_in[0];
    const float* ec1_w  = (const float*)d_in[1];
    const float* ec1_b  = (const float*)d_in[2];
    const float* ec2_w  = (const float*)d_in[3];
    const float* ec2_b  = (const float*)d_in[4];
    const float* ec3_w  = (const float*)d_in[5];
    const float* ec3_b  = (const float*)d_in[6];
    const float* ec4_w  = (const float*)d_in[7];
    const float* ec4_b  = (const float*)d_in[8];
    const float* er0a_w = (const float*)d_in[9];
    const float* er0b_w = (const float*)d_in[10];
    const float* er1a_w = (const float*)d_in[11];
    const float* er1b_w = (const float*)d_in[12];
    const float* pvq_w  = (const float*)d_in[13];
    const float* pvq_b  = (const float*)d_in[14];
    const float* cbk    = (const float*)d_in[15];
    const float* dc1_w  = (const float*)d_in[16];
    const float* dc1_b  = (const float*)d_in[17];
    const float* dr0a_w = (const float*)d_in[18];
    const float* dr0b_w = (const float*)d_in[19];
    const float* dr1a_w = (const float*)d_in[20];
    const float* dr1b_w = (const float*)d_in[21];
    const float* dt1_w  = (const float*)d_in[22];
    const float* dt1_b  = (const float*)d_in[23];
    const float* dt2_w  = (const float*)d_in[24];
    const float* dt2_b  = (const float*)d_in[25];
    const float* dt3_w  = (const float*)d_in[26];
    const float* dt3_b  = (const float*)d_in[27];

    float* out = (float*)d_out;
    ushort_t* P = (ushort_t*)d_ws;

    // ---- activation arena (ushort offsets) ----
    ushort_t* a1h = P;              // 33,554,432
    ushort_t* a1l = P + 33554432;
    ushort_t* a2h = P + 67108864;   // 16,777,216
    ushort_t* a2l = P + 83886080;
    // reuse zone [0, 67108864) once a1 is dead (after ec2):
    ushort_t* a3h = P;              //  4,194,304
    ushort_t* a3l = P + 4194304;
    ushort_t* a4h = P + 8388608;
    ushort_t* a4l = P + 12582912;
    ushort_t* th  = P + 16777216;   //  1,048,576
    ushort_t* tl  = P + 17825792;
    ushort_t* zh  = P + 18874368;   //  2,097,152
    ushort_t* zl  = P + 20971520;
    ushort_t* qb  = P + 23068672;   //  2,097,152
    ushort_t* d1  = P + 25165824;   //  4,194,304
    ushort_t* t2  = P + 29360128;   //  1,048,576
    ushort_t* u1  = P + 30408704;   //  8,388,608
    ushort_t* u2  = P + 38797312;   // 33,554,432 (overlaps dead a2 region)

    // ---- weight arena ----
    size_t wc = 104857600;
    auto walloc = [&](size_t n) { ushort_t* p = P + wc; wc += n; return p; };
    ushort_t* W_ec2h = walloc(73728);  ushort_t* W_ec2l = walloc(73728);
    ushort_t* W_ec3h = walloc(147456); ushort_t* W_ec3l = walloc(147456);
    ushort_t* W_ec4h = walloc(147456); ushort_t* W_ec4l = walloc(147456);
    ushort_t* W_r0ah = walloc(36864);  ushort_t* W_r0al = walloc(36864);
    ushort_t* W_r0bh = walloc(4096);   ushort_t* W_r0bl = walloc(4096);
    ushort_t* W_r1ah = walloc(36864);  ushort_t* W_r1al = walloc(36864);
    ushort_t* W_r1bh = walloc(4096);   ushort_t* W_r1bl = walloc(4096);
    ushort_t* W_pvqh = walloc(8192);   ushort_t* W_pvql = walloc(8192);
    ushort_t* W_dc1  = walloc(73728);
    ushort_t* W_d0a  = walloc(36864);
    ushort_t* W_d0b  = walloc(4096);
    ushort_t* W_d1a  = walloc(36864);
    ushort_t* W_d1b  = walloc(4096);
    ushort_t* W_dt1  = walloc(73728);
    ushort_t* W_dt2  = walloc(36864);
    ushort_t* W_dt3  = walloc(1728);

    float* miscF = (float*)(P + 112000000);
    float* cn = miscF;                    // 512
    float* ls = miscF + 512;              // 1
    unsigned* hist = (unsigned*)(miscF + 513); // 512

    // ---- tap tables ----
    Taps t9 = {}; t9.n = 9;
    for (int kh = 0; kh < 3; kh++)
        for (int kw = 0; kw < 3; kw++) {
            int i = kh * 3 + kw;
            t9.dy[i] = kh - 1; t9.dx[i] = kw - 1; t9.wi[i] = i;
        }
    Taps t1 = {}; t1.n = 1;
    Taps tp[4];
    for (int po = 0; po < 2; po++)
        for (int pw = 0; pw < 2; pw++) {
            int khs[2], dhs[2], nh, kws[2], dws[2], nw;
            if (po == 0) { nh = 1; khs[0] = 1; dhs[0] = 0; }
            else         { nh = 2; khs[0] = 0; dhs[0] = 1; khs[1] = 2; dhs[1] = 0; }
            if (pw == 0) { nw = 1; kws[0] = 1; dws[0] = 0; }
            else         { nw = 2; kws[0] = 0; dws[0] = 1; kws[1] = 2; dws[1] = 0; }
            Taps T = {}; T.n = 0;
            for (int a = 0; a < nh; a++)
                for (int c = 0; c < nw; c++) {
                    T.dy[T.n] = dhs[a]; T.dx[T.n] = dws[c];
                    T.wi[T.n] = khs[a] * 3 + kws[c]; T.n++;
                }
            tp[po * 2 + pw] = T;
        }

    // ---- prep ----
    hipMemsetAsync(ls, 0, 4 * 513, stream);
    cnorm_k<<<8, 64, 0, stream>>>(cbk, cn);
    auto prep = [&](const float* src, ushort_t* dh, ushort_t* dl, int O, int I, int T, int mode) {
        int n = O * I * T;
        prep_k<<<(n + 255) / 256, 256, 0, stream>>>(src, dh, dl, O, I, T, mode);
    };
    prep(ec2_w, W_ec2h, W_ec2l, 128, 64, 9, 0);
    prep(ec3_w, W_ec3h, W_ec3l, 128, 128, 9, 0);
    prep(ec4_w, W_ec4h, W_ec4l, 128, 128, 9, 0);
    prep(er0a_w, W_r0ah, W_r0al, 32, 128, 9, 0);
    prep(er0b_w, W_r0bh, W_r0bl, 128, 32, 1, 0);
    prep(er1a_w, W_r1ah, W_r1al, 32, 128, 9, 0);
    prep(er1b_w, W_r1bh, W_r1bl, 128, 32, 1, 0);
    prep(pvq_w, W_pvqh, W_pvql, 64, 128, 1, 0);
    prep(dc1_w, W_dc1, nullptr, 128, 64, 9, 0);
    prep(dr0a_w, W_d0a, nullptr, 32, 128, 9, 0);
    prep(dr0b_w, W_d0b, nullptr, 128, 32, 1, 0);
    prep(dr1a_w, W_d1a, nullptr, 32, 128, 9, 0);
    prep(dr1b_w, W_d1b, nullptr, 128, 32, 1, 0);
    prep(dt1_w, W_dt1, nullptr, 64, 128, 9, 1);
    prep(dt2_w, W_dt2, nullptr, 64, 64, 9, 1);
    prep(dt3_w, W_dt3, nullptr, 3, 64, 9, 1);

    // ---- encoder ----
    ec1_k<<<dim3(64, 4, 32), 256, 0, stream>>>(x, ec1_w, ec1_b, a1h, a1l);
    // ec2: 64->128, s2, 128x128 -> 64x64
    mconv<2, 2, 1, 1, 0, 0><<<dim3(64, 2, 32), 256, 0, stream>>>(
        a1h, a1l, W_ec2h, W_ec2l, ec2_b, nullptr, nullptr, a2h, a2l, nullptr,
        64, 128, 128, 128, 64, 64, 2, 9 * 64, 1, 0, 0, 64, 64, t9);
    // ec3: 128->128, s2, 64x64 -> 32x32
    mconv<2, 2, 1, 1, 0, 0><<<dim3(16, 2, 32), 256, 0, stream>>>(
        a2h, a2l, W_ec3h, W_ec3l, ec3_b, nullptr, nullptr, a3h, a3l, nullptr,
        128, 64, 64, 128, 32, 32, 2, 9 * 128, 1, 0, 0, 32, 32, t9);
    // ec4: 128->128, s1
    mconv<2, 2, 1, 1, 0, 0><<<dim3(16, 2, 32), 256, 0, stream>>>(
        a3h, a3l, W_ec4h, W_ec4l, ec4_b, nullptr, nullptr, a4h, a4l, nullptr,
        128, 32, 32, 128, 32, 32, 1, 9 * 128, 1, 0, 0, 32, 32, t9);
    // enc res block 0
    mconv<1, 4, 1, 1, 0, 0><<<dim3(8, 1, 32), 256, 0, stream>>>(
        a4h, a4l, W_r0ah, W_r0al, nullptr, nullptr, nullptr, th, tl, nullptr,
        128, 32, 32, 32, 32, 32, 1, 9 * 128, 1, 0, 0, 32, 32, t9);
    mconv<2, 2, 1, 1, 1, 0><<<dim3(16, 2, 32), 256, 0, stream>>>(
        th, tl, W_r0bh, W_r0bl, nullptr, a4h, a4l, a4h, a4l, nullptr,
        32, 32, 32, 128, 32, 32, 1, 32, 1, 0, 0, 32, 32, t1);
    // enc res block 1
    mconv<1, 4, 1, 1, 0, 0><<<dim3(8, 1, 32), 256, 0, stream>>>(
        a4h, a4l, W_r1ah, W_r1al, nullptr, nullptr, nullptr, th, tl, nullptr,
        128, 32, 32, 32, 32, 32, 1, 9 * 128, 1, 0, 0, 32, 32, t9);
    mconv<2, 2, 1, 1, 1, 0><<<dim3(16, 2, 32), 256, 0, stream>>>(
        th, tl, W_r1bh, W_r1bl, nullptr, a4h, a4l, a4h, a4l, nullptr,
        32, 32, 32, 128, 32, 32, 1, 32, 1, 0, 0, 32, 32, t1);
    // pre-VQ 1x1 (final res-stack relu folded in)
    mconv<2, 2, 1, 1, 0, 0><<<dim3(16, 1, 32), 256, 0, stream>>>(
        a4h, a4l, W_pvqh, W_pvql, pvq_b, nullptr, nullptr, zh, zl, nullptr,
        128, 32, 32, 64, 32, 32, 1, 128, 1, 0, 0, 32, 32, t1);

    // ---- VQ ----
    vq_k<<<128, 256, 0, stream>>>(zh, zl, cbk, cn, qb, ls, hist);

    // ---- decoder ----
    mconv<2, 2, 0, 0, 0, 0><<<dim3(16, 2, 32), 256, 0, stream>>>(
        qb, nullptr, W_dc1, nullptr, dc1_b, nullptr, nullptr, d1, nullptr, nullptr,
        64, 32, 32, 128, 32, 32, 1, 9 * 64, 1, 0, 0, 32, 32, t9);
    mconv<1, 4, 0, 1, 0, 0><<<dim3(8, 1, 32), 256, 0, stream>>>(
        d1, nullptr, W_d0a, nullptr, nullptr, nullptr, nullptr, t2, nullptr, nullptr,
        128, 32, 32, 32, 32, 32, 1, 9 * 128, 1, 0, 0, 32, 32, t9);
    mconv<2, 2, 0, 1, 1, 0><<<dim3(16, 2, 32), 256, 0, stream>>>(
        t2, nullptr, W_d0b, nullptr, nullptr, d1, nullptr, d1, nullptr, nullptr,
        32, 32, 32, 128, 32, 32, 1, 32, 1, 0, 0, 32, 32, t1);
    mconv<1, 4, 0, 1, 0, 0><<<dim3(8, 1, 32), 256, 0, stream>>>(
        d1, nullptr, W_d1a, nullptr, nullptr, nullptr, nullptr, t2, nullptr, nullptr,
        128, 32, 32, 32, 32, 32, 1, 9 * 128, 1, 0, 0, 32, 32, t9);
    mconv<2, 2, 0, 1, 1, 0><<<dim3(16, 2, 32), 256, 0, stream>>>(
        t2, nullptr, W_d1b, nullptr, nullptr, d1, nullptr, d1, nullptr, nullptr,
        32, 32, 32, 128, 32, 32, 1, 32, 1, 0, 0, 32, 32, t1);
    // dt1 (4 parity sub-convs), res-stack relu folded via RELU_IN
    for (int par = 0; par < 4; ++par)
        mconv<2, 2, 0, 1, 0, 0><<<dim3(16, 1, 32), 256, 0, stream>>>(
            d1, nullptr, W_dt1, nullptr, dt1_b, nullptr, nullptr, u1, nullptr, nullptr,
            128, 32, 32, 64, 32, 32, 1, 9 * 128, 2, par >> 1, par & 1, 64, 64, tp[par]);
    // dt2
    for (int par = 0; par < 4; ++par)
        mconv<2, 2, 0, 1, 0, 0><<<dim3(64, 1, 32), 256, 0, stream>>>(
            u1, nullptr, W_dt2, nullptr, dt2_b, nullptr, nullptr, u2, nullptr, nullptr,
            64, 64, 64, 64, 64, 64, 1, 9 * 64, 2, par >> 1, par & 1, 128, 128, tp[par]);
    // dt3 -> fp32 NCHW output
    for (int par = 0; par < 4; ++par)
        mconv<1, 4, 0, 1, 0, 1><<<dim3(128, 1, 32), 256, 0, stream>>>(
            u2, nullptr, W_dt3, nullptr, dt3_b, nullptr, nullptr, nullptr, nullptr, out + 1,
            64, 128, 128, 3, 128, 128, 1, 9 * 64, 2, par >> 1, par & 1, 256, 256, tp[par]);

    // ---- scalars ----
    fin_k<<<1, 512, 0, stream>>>(hist, ls, out, out_size);
}